// Round 1
// baseline (344.466 us; speedup 1.0000x reference)
//
#include <hip/hip_runtime.h>
#include <hip/hip_bf16.h>

typedef _Float16 f16;
typedef _Float16 f16x8 __attribute__((ext_vector_type(8)));
typedef _Float16 f16x4 __attribute__((ext_vector_type(4)));
typedef float f32x4 __attribute__((ext_vector_type(4)));

#define MFMA_F16(a, b, c) __builtin_amdgcn_mfma_f32_16x16x32_f16((a), (b), (c), 0, 0, 0)

static constexpr int S_TOK = 2048;
static constexpr int N_HEAD = 16;
static constexpr int N_KV = 4;
static constexpr int HD = 64;
// softmax uses exp2: exp(s*0.125) == exp2(s*0.125*log2(e))
static constexpr float SCL2E = 0.125f * 1.4426950408889634f;

// ---------------------------------------------------------------------------
// Kernel 1: fused QKV projection + bias + partial RoPE.
//   x [4096,1024] fp32  @  [q_w|k_w|v_w]  -> q_ws/k_ws/v_ws fp16
//   q_ws: [b][h][s][hd], k_ws: [b][kv][s][hd], v_ws TRANSPOSED: [b][kv][hd][s]
// grid (64 m-tiles, 24 n-tiles), block 256 (4 waves, each 16 rows x 64 cols)
// ---------------------------------------------------------------------------
__global__ __launch_bounds__(256) void k_qkv(
    const float* __restrict__ x, const float* __restrict__ cosp,
    const float* __restrict__ sinp, const float* __restrict__ q_w,
    const float* __restrict__ q_b, const float* __restrict__ k_w,
    const float* __restrict__ v_w, const float* __restrict__ v_b,
    f16* __restrict__ q_ws, f16* __restrict__ k_ws, f16* __restrict__ v_ws) {
  __shared__ f16 wb[64][72];  // [n][k], +8 pad: b128 reads 16B-aligned, 2-way banks
  const int tid = threadIdx.x;
  const int wave = tid >> 6, lane = tid & 63;
  const int l16 = lane & 15, g = lane >> 4;
  const int m0 = blockIdx.x * 64;
  const int n0 = blockIdx.y * 64;

  const float* W;
  int ldW, nloc, mode;  // mode 0=q 1=k 2=v
  if (n0 < 1024) { W = q_w; ldW = 1024; nloc = n0; mode = 0; }
  else if (n0 < 1280) { W = k_w; ldW = 256; nloc = n0 - 1024; mode = 1; }
  else { W = v_w; ldW = 256; nloc = n0 - 1280; mode = 2; }

  f32x4 acc[4] = {};
  const int kk = (tid >> 4) * 4;  // k within tile (0..60)
  const int nn = (tid & 15) * 4;  // n within tile (0..60)

  for (int k0 = 0; k0 < 1024; k0 += 64) {
    const float* wp = W + (size_t)(k0 + kk) * ldW + nloc + nn;
    float4 w0 = *(const float4*)(wp);
    float4 w1 = *(const float4*)(wp + ldW);
    float4 w2 = *(const float4*)(wp + 2 * ldW);
    float4 w3 = *(const float4*)(wp + 3 * ldW);
    __syncthreads();
    *(f16x4*)&wb[nn + 0][kk] = f16x4{(f16)w0.x, (f16)w1.x, (f16)w2.x, (f16)w3.x};
    *(f16x4*)&wb[nn + 1][kk] = f16x4{(f16)w0.y, (f16)w1.y, (f16)w2.y, (f16)w3.y};
    *(f16x4*)&wb[nn + 2][kk] = f16x4{(f16)w0.z, (f16)w1.z, (f16)w2.z, (f16)w3.z};
    *(f16x4*)&wb[nn + 3][kk] = f16x4{(f16)w0.w, (f16)w1.w, (f16)w2.w, (f16)w3.w};
    __syncthreads();
    const float* xp = x + (size_t)(m0 + wave * 16 + l16) * 1024 + k0 + g * 8;
#pragma unroll
    for (int ks = 0; ks < 2; ++ks) {
      float4 a0 = *(const float4*)(xp + ks * 32);
      float4 a1 = *(const float4*)(xp + ks * 32 + 4);
      f16x8 af = {(f16)a0.x, (f16)a0.y, (f16)a0.z, (f16)a0.w,
                  (f16)a1.x, (f16)a1.y, (f16)a1.z, (f16)a1.w};
#pragma unroll
      for (int n = 0; n < 4; ++n) {
        f16x8 bf = *(const f16x8*)&wb[n * 16 + l16][ks * 32 + g * 8];
        acc[n] = MFMA_F16(af, bf, acc[n]);
      }
    }
  }

  // bias (q and v only)
  if (mode == 0) {
#pragma unroll
    for (int n = 0; n < 4; ++n) {
      float bsc = q_b[n0 + n * 16 + l16];
#pragma unroll
      for (int r = 0; r < 4; ++r) acc[n][r] += bsc;
    }
  } else if (mode == 2) {
#pragma unroll
    for (int n = 0; n < 4; ++n) {
      float bsc = v_b[nloc + n * 16 + l16];
#pragma unroll
      for (int r = 0; r < 4; ++r) acc[n][r] += bsc;
    }
  }
  // RoPE on q,k: head-rel cols 0..15 (frag0) pair with 16..31 (frag1); cos/sin
  // duplicated across halves so cos[d]==cos[d+16].
  if (mode < 2) {
#pragma unroll
    for (int r = 0; r < 4; ++r) {
      int row = m0 + wave * 16 + g * 4 + r;
      int bb = row >> 11, ss = row & 2047;
      float c = cosp[((size_t)bb * S_TOK + ss) * 32 + l16];
      float sn = sinp[((size_t)bb * S_TOK + ss) * 32 + l16];
      float v0 = acc[0][r], v1 = acc[1][r];
      acc[0][r] = v0 * c - v1 * sn;
      acc[1][r] = v1 * c + v0 * sn;
    }
  }
#pragma unroll
  for (int n = 0; n < 4; ++n) {
#pragma unroll
    for (int r = 0; r < 4; ++r) {
      int row = m0 + wave * 16 + g * 4 + r;
      int bb = row >> 11, ss = row & 2047;
      f16 val = (f16)acc[n][r];
      if (mode == 0) {
        int col = n0 + n * 16 + l16;
        int h = col >> 6, hd = col & 63;
        q_ws[(((size_t)bb * N_HEAD + h) * S_TOK + ss) * HD + hd] = val;
      } else {
        int col = nloc + n * 16 + l16;
        int kh = col >> 6, hd = col & 63;
        if (mode == 1)
          k_ws[(((size_t)bb * N_KV + kh) * S_TOK + ss) * HD + hd] = val;
        else
          v_ws[(((size_t)bb * N_KV + kh) * HD + hd) * S_TOK + ss] = val;
      }
    }
  }
}

// ---------------------------------------------------------------------------
// Kernel 2: attention. One wave owns 32 Q-rows of one head; no block barriers.
// Pass A: l[row] = sum_t exp(s*SCALE)  (no-max softmax: |s|<~8, safe in fp32)
// Pass B: recompute scores (bitwise identical), p = exp*1/l; write fp32 probs
//         (coalesced via LDS roundtrip) and accumulate O += P@V via MFMA.
// grid 512 (32 heads x 16 row-tiles of 128), block 256 (4 indep waves)
// ---------------------------------------------------------------------------
__global__ __launch_bounds__(256) void k_attn(
    const f16* __restrict__ q_ws, const f16* __restrict__ k_ws,
    const f16* __restrict__ v_ws, f16* __restrict__ o_ws,
    float* __restrict__ probs) {
  __shared__ f16 plds_all[4][32][72];
  const int tid = threadIdx.x;
  const int wave = tid >> 6, lane = tid & 63;
  const int l16 = lane & 15, g = lane >> 4;
  const int head = blockIdx.x >> 4;  // b*16+h
  const int rt = blockIdx.x & 15;
  const int b = head >> 4, h = head & 15, kvh = h >> 2;
  const int qrow0 = rt * 128 + wave * 32;

  const f16* qb = q_ws + ((size_t)head * S_TOK + qrow0) * HD;
  const f16* kb = k_ws + (size_t)(b * N_KV + kvh) * S_TOK * HD;
  const f16* vb = v_ws + (size_t)(b * N_KV + kvh) * HD * S_TOK;  // [hd][s]
  float* pout = probs + (size_t)head * S_TOK * S_TOK + (size_t)qrow0 * S_TOK;
  f16(*plds)[72] = plds_all[wave];

  f16x8 qf[2][2];
#pragma unroll
  for (int mf = 0; mf < 2; ++mf)
#pragma unroll
    for (int ks = 0; ks < 2; ++ks)
      qf[mf][ks] = *(const f16x8*)(qb + (mf * 16 + l16) * HD + ks * 32 + g * 8);

  // ---- pass A: row sums of exp ----
  float lsum[2][4] = {};
  for (int kt = 0; kt < 32; ++kt) {
    const f16* kp = kb + (size_t)kt * 64 * HD;
    f16x8 kf[4][2];
#pragma unroll
    for (int n = 0; n < 4; ++n)
#pragma unroll
      for (int ks = 0; ks < 2; ++ks)
        kf[n][ks] = *(const f16x8*)(kp + (n * 16 + l16) * HD + ks * 32 + g * 8);
#pragma unroll
    for (int mf = 0; mf < 2; ++mf)
#pragma unroll
      for (int n = 0; n < 4; ++n) {
        f32x4 s = {};
        s = MFMA_F16(qf[mf][0], kf[n][0], s);
        s = MFMA_F16(qf[mf][1], kf[n][1], s);
#pragma unroll
        for (int r = 0; r < 4; ++r) lsum[mf][r] += exp2f(s[r] * SCL2E);
      }
  }
#pragma unroll
  for (int mf = 0; mf < 2; ++mf)
#pragma unroll
    for (int r = 0; r < 4; ++r) {
      float v = lsum[mf][r];
      v += __shfl_xor(v, 1, 64);
      v += __shfl_xor(v, 2, 64);
      v += __shfl_xor(v, 4, 64);
      v += __shfl_xor(v, 8, 64);
      lsum[mf][r] = 1.0f / v;  // now holds 1/l for this lane's rows
    }

  // ---- pass B: probs write + PV ----
  f32x4 oacc[2][4] = {};
  const int orow = lane >> 3, oq = lane & 7;
  for (int kt = 0; kt < 32; ++kt) {
    const f16* kp = kb + (size_t)kt * 64 * HD;
    f16x8 kf[4][2];
#pragma unroll
    for (int n = 0; n < 4; ++n)
#pragma unroll
      for (int ks = 0; ks < 2; ++ks)
        kf[n][ks] = *(const f16x8*)(kp + (n * 16 + l16) * HD + ks * 32 + g * 8);
#pragma unroll
    for (int mf = 0; mf < 2; ++mf)
#pragma unroll
      for (int n = 0; n < 4; ++n) {
        f32x4 s = {};
        s = MFMA_F16(qf[mf][0], kf[n][0], s);
        s = MFMA_F16(qf[mf][1], kf[n][1], s);
#pragma unroll
        for (int r = 0; r < 4; ++r) {
          float p = exp2f(s[r] * SCL2E) * lsum[mf][r];
          plds[mf * 16 + g * 4 + r][n * 16 + l16] = (f16)p;
        }
      }
    asm volatile("s_waitcnt lgkmcnt(0)" ::: "memory");  // cross-lane LDS visibility
    // P fragments for PV (A-layout: row=l16, k=key contiguous)
    f16x8 pa[2][2];
#pragma unroll
    for (int mf = 0; mf < 2; ++mf)
#pragma unroll
      for (int ks = 0; ks < 2; ++ks)
        pa[mf][ks] = *(const f16x8*)&plds[mf * 16 + l16][ks * 32 + g * 8];
    f16x8 vf[4][2];
#pragma unroll
    for (int nh = 0; nh < 4; ++nh)
#pragma unroll
      for (int ks = 0; ks < 2; ++ks)
        vf[nh][ks] = *(const f16x8*)(vb + (size_t)(nh * 16 + l16) * S_TOK +
                                     kt * 64 + ks * 32 + g * 8);
#pragma unroll
    for (int mf = 0; mf < 2; ++mf)
#pragma unroll
      for (int nh = 0; nh < 4; ++nh) {
        oacc[mf][nh] = MFMA_F16(pa[mf][0], vf[nh][0], oacc[mf][nh]);
        oacc[mf][nh] = MFMA_F16(pa[mf][1], vf[nh][1], oacc[mf][nh]);
      }
    // coalesced fp32 probs write: 8 lanes cover one row's 64 keys (256B)
#pragma unroll
    for (int it = 0; it < 4; ++it) {
      int rr = it * 8 + orow;
      f16x8 pv = *(const f16x8*)&plds[rr][oq * 8];
      f32x4 lo = {(float)pv[0], (float)pv[1], (float)pv[2], (float)pv[3]};
      f32x4 hi = {(float)pv[4], (float)pv[5], (float)pv[6], (float)pv[7]};
      float* dst = pout + (size_t)rr * S_TOK + kt * 64 + oq * 8;
      *(f32x4*)dst = lo;
      *(f32x4*)(dst + 4) = hi;
    }
    asm volatile("" ::: "memory");  // keep next iter's LDS writes after these reads
  }
  // O -> o_ws [b][s][h*64+hd] fp16
#pragma unroll
  for (int mf = 0; mf < 2; ++mf)
#pragma unroll
    for (int nh = 0; nh < 4; ++nh)
#pragma unroll
      for (int r = 0; r < 4; ++r) {
        int srow = qrow0 + mf * 16 + g * 4 + r;
        o_ws[((size_t)b * S_TOK + srow) * 1024 + h * HD + nh * 16 + l16] =
            (f16)oacc[mf][nh][r];
      }
}

// ---------------------------------------------------------------------------
// Kernel 3: O projection. attn(fp16)[4096,1024] @ o_w + o_b -> d_out fp32
// ---------------------------------------------------------------------------
__global__ __launch_bounds__(256) void k_oproj(
    const f16* __restrict__ a, const float* __restrict__ o_w,
    const float* __restrict__ o_b, float* __restrict__ out) {
  __shared__ f16 wb[64][72];
  const int tid = threadIdx.x;
  const int wave = tid >> 6, lane = tid & 63;
  const int l16 = lane & 15, g = lane >> 4;
  const int m0 = blockIdx.x * 64, n0 = blockIdx.y * 64;
  f32x4 acc[4] = {};
  const int kk = (tid >> 4) * 4, nn = (tid & 15) * 4;
  for (int k0 = 0; k0 < 1024; k0 += 64) {
    const float* wp = o_w + (size_t)(k0 + kk) * 1024 + n0 + nn;
    float4 w0 = *(const float4*)(wp);
    float4 w1 = *(const float4*)(wp + 1024);
    float4 w2 = *(const float4*)(wp + 2048);
    float4 w3 = *(const float4*)(wp + 3072);
    __syncthreads();
    *(f16x4*)&wb[nn + 0][kk] = f16x4{(f16)w0.x, (f16)w1.x, (f16)w2.x, (f16)w3.x};
    *(f16x4*)&wb[nn + 1][kk] = f16x4{(f16)w0.y, (f16)w1.y, (f16)w2.y, (f16)w3.y};
    *(f16x4*)&wb[nn + 2][kk] = f16x4{(f16)w0.z, (f16)w1.z, (f16)w2.z, (f16)w3.z};
    *(f16x4*)&wb[nn + 3][kk] = f16x4{(f16)w0.w, (f16)w1.w, (f16)w2.w, (f16)w3.w};
    __syncthreads();
    const f16* ap = a + (size_t)(m0 + wave * 16 + l16) * 1024 + k0 + g * 8;
#pragma unroll
    for (int ks = 0; ks < 2; ++ks) {
      f16x8 af = *(const f16x8*)(ap + ks * 32);
#pragma unroll
      for (int n = 0; n < 4; ++n) {
        f16x8 bf = *(const f16x8*)&wb[n * 16 + l16][ks * 32 + g * 8];
        acc[n] = MFMA_F16(af, bf, acc[n]);
      }
    }
  }
#pragma unroll
  for (int n = 0; n < 4; ++n) {
    float bsc = o_b[n0 + n * 16 + l16];
#pragma unroll
    for (int r = 0; r < 4; ++r) {
      int row = m0 + wave * 16 + g * 4 + r;
      out[(size_t)row * 1024 + n0 + n * 16 + l16] = acc[n][r] + bsc;
    }
  }
}

extern "C" void kernel_launch(void* const* d_in, const int* in_sizes, int n_in,
                              void* d_out, int out_size, void* d_ws,
                              size_t ws_size, hipStream_t stream) {
  (void)in_sizes; (void)n_in; (void)out_size; (void)ws_size;
  const float* x    = (const float*)d_in[0];
  const float* cosp = (const float*)d_in[1];
  const float* sinp = (const float*)d_in[2];
  const float* q_w  = (const float*)d_in[3];
  const float* q_b  = (const float*)d_in[4];
  const float* k_w  = (const float*)d_in[5];
  const float* v_w  = (const float*)d_in[6];
  const float* v_b  = (const float*)d_in[7];
  const float* o_w  = (const float*)d_in[8];
  const float* o_b  = (const float*)d_in[9];

  f16* q_ws = (f16*)d_ws;              // 4,194,304 halfs
  f16* k_ws = q_ws + 4194304;          // 1,048,576
  f16* v_ws = k_ws + 1048576;          // 1,048,576 (transposed [kv][hd][s])
  f16* o_ws = v_ws + 1048576;          // 4,194,304
  float* out = (float*)d_out;          // attn_output [0, 4194304)
  float* probs = out + 4194304;        // attn_weights

  k_qkv<<<dim3(64, 24), 256, 0, stream>>>(x, cosp, sinp, q_w, q_b, k_w, v_w,
                                          v_b, q_ws, k_ws, v_ws);
  k_attn<<<dim3(512), 256, 0, stream>>>(q_ws, k_ws, v_ws, o_ws, probs);
  k_oproj<<<dim3(64, 16), 256, 0, stream>>>(o_ws, o_w, o_b, out);
}

// Round 2
// 298.136 us; speedup vs baseline: 1.1554x; 1.1554x over previous
//
#include <hip/hip_runtime.h>
#include <hip/hip_bf16.h>

typedef _Float16 f16;
typedef _Float16 f16x8 __attribute__((ext_vector_type(8)));
typedef _Float16 f16x4 __attribute__((ext_vector_type(4)));
typedef float f32x4 __attribute__((ext_vector_type(4)));

#define MFMA_F16(a, b, c) __builtin_amdgcn_mfma_f32_16x16x32_f16((a), (b), (c), 0, 0, 0)

static constexpr int S_TOK = 2048;
static constexpr int N_HEAD = 16;
static constexpr int N_KV = 4;
static constexpr int HD = 64;
// softmax uses exp2: exp(s*0.125) == exp2(s*0.125*log2(e))
static constexpr float SCL2E = 0.125f * 1.4426950408889634f;

// ws element offsets (f16 units)
static constexpr size_t OFF_X16 = 0;                      // 4,194,304
static constexpr size_t OFF_QW = 4194304;                 // 1,048,576
static constexpr size_t OFF_KW = OFF_QW + 1048576;        // 262,144
static constexpr size_t OFF_VW = OFF_KW + 262144;         // 262,144
static constexpr size_t OFF_OW = OFF_VW + 262144;         // 1,048,576
static constexpr size_t OFF_QS = OFF_OW + 1048576;        // 4,194,304
static constexpr size_t OFF_KS = OFF_QS + 4194304;        // 1,048,576
static constexpr size_t OFF_VS = OFF_KS + 1048576;        // 1,048,576
static constexpr size_t OFF_OS = OFF_VS + 1048576;        // 4,194,304
static constexpr size_t CVT_TOTAL = OFF_OW + 1048576;     // 6,815,744 elems

// ---------------------------------------------------------------------------
// Kernel 0: fp32 -> f16 conversion of x and all four weight matrices.
// ---------------------------------------------------------------------------
__global__ __launch_bounds__(256) void k_cvt(
    const float* __restrict__ x, const float* __restrict__ qw,
    const float* __restrict__ kw, const float* __restrict__ vw,
    const float* __restrict__ ow, f16* __restrict__ dst) {
  size_t i = ((size_t)blockIdx.x * 256 + threadIdx.x) * 4;
  if (i >= CVT_TOTAL) return;
  const float* src;
  size_t off;
  if (i < OFF_QW) { src = x; off = i; }
  else if (i < OFF_KW) { src = qw; off = i - OFF_QW; }
  else if (i < OFF_VW) { src = kw; off = i - OFF_KW; }
  else if (i < OFF_OW) { src = vw; off = i - OFF_VW; }
  else { src = ow; off = i - OFF_OW; }
  float4 v = *(const float4*)(src + off);
  *(f16x4*)(dst + i) = f16x4{(f16)v.x, (f16)v.y, (f16)v.z, (f16)v.w};
}

// ---------------------------------------------------------------------------
// Kernel 1: fused QKV projection + bias + partial RoPE (f16 inputs).
//   q_ws: [b][h][s][hd], k_ws: [b][kv][s][hd], v_ws TRANSPOSED: [b][kv][hd][s]
// ---------------------------------------------------------------------------
__global__ __launch_bounds__(256) void k_qkv(
    const f16* __restrict__ x, const float* __restrict__ cosp,
    const float* __restrict__ sinp, const f16* __restrict__ q_w,
    const float* __restrict__ q_b, const f16* __restrict__ k_w,
    const f16* __restrict__ v_w, const float* __restrict__ v_b,
    f16* __restrict__ q_ws, f16* __restrict__ k_ws, f16* __restrict__ v_ws) {
  __shared__ f16 wb[64][72];
  const int tid = threadIdx.x;
  const int wave = tid >> 6, lane = tid & 63;
  const int l16 = lane & 15, g = lane >> 4;
  const int m0 = blockIdx.x * 64;
  const int n0 = blockIdx.y * 64;

  const f16* W;
  int ldW, nloc, mode;  // mode 0=q 1=k 2=v
  if (n0 < 1024) { W = q_w; ldW = 1024; nloc = n0; mode = 0; }
  else if (n0 < 1280) { W = k_w; ldW = 256; nloc = n0 - 1024; mode = 1; }
  else { W = v_w; ldW = 256; nloc = n0 - 1280; mode = 2; }

  f32x4 acc[4] = {};
  const int kk = (tid >> 4) * 4;  // k within tile
  const int nn = (tid & 15) * 4;  // n within tile

  for (int k0 = 0; k0 < 1024; k0 += 64) {
    const f16* wp = W + (size_t)(k0 + kk) * ldW + nloc + nn;
    f16x4 w0 = *(const f16x4*)(wp);
    f16x4 w1 = *(const f16x4*)(wp + ldW);
    f16x4 w2 = *(const f16x4*)(wp + 2 * ldW);
    f16x4 w3 = *(const f16x4*)(wp + 3 * ldW);
    __syncthreads();
    *(f16x4*)&wb[nn + 0][kk] = f16x4{w0[0], w1[0], w2[0], w3[0]};
    *(f16x4*)&wb[nn + 1][kk] = f16x4{w0[1], w1[1], w2[1], w3[1]};
    *(f16x4*)&wb[nn + 2][kk] = f16x4{w0[2], w1[2], w2[2], w3[2]};
    *(f16x4*)&wb[nn + 3][kk] = f16x4{w0[3], w1[3], w2[3], w3[3]};
    __syncthreads();
    const f16* xp = x + (size_t)(m0 + wave * 16 + l16) * 1024 + k0 + g * 8;
#pragma unroll
    for (int ks = 0; ks < 2; ++ks) {
      f16x8 af = *(const f16x8*)(xp + ks * 32);
#pragma unroll
      for (int n = 0; n < 4; ++n) {
        f16x8 bf = *(const f16x8*)&wb[n * 16 + l16][ks * 32 + g * 8];
        acc[n] = MFMA_F16(af, bf, acc[n]);
      }
    }
  }

  if (mode == 0) {
#pragma unroll
    for (int n = 0; n < 4; ++n) {
      float bsc = q_b[n0 + n * 16 + l16];
#pragma unroll
      for (int r = 0; r < 4; ++r) acc[n][r] += bsc;
    }
  } else if (mode == 2) {
#pragma unroll
    for (int n = 0; n < 4; ++n) {
      float bsc = v_b[nloc + n * 16 + l16];
#pragma unroll
      for (int r = 0; r < 4; ++r) acc[n][r] += bsc;
    }
  }
  if (mode < 2) {  // RoPE: frag0 cols pair with frag1 cols (d, d+16)
#pragma unroll
    for (int r = 0; r < 4; ++r) {
      int row = m0 + wave * 16 + g * 4 + r;
      int bb = row >> 11, ss = row & 2047;
      float c = cosp[((size_t)bb * S_TOK + ss) * 32 + l16];
      float sn = sinp[((size_t)bb * S_TOK + ss) * 32 + l16];
      float v0 = acc[0][r], v1 = acc[1][r];
      acc[0][r] = v0 * c - v1 * sn;
      acc[1][r] = v1 * c + v0 * sn;
    }
  }
#pragma unroll
  for (int n = 0; n < 4; ++n) {
#pragma unroll
    for (int r = 0; r < 4; ++r) {
      int row = m0 + wave * 16 + g * 4 + r;
      int bb = row >> 11, ss = row & 2047;
      f16 val = (f16)acc[n][r];
      if (mode == 0) {
        int col = n0 + n * 16 + l16;
        int h = col >> 6, hd = col & 63;
        q_ws[(((size_t)bb * N_HEAD + h) * S_TOK + ss) * HD + hd] = val;
      } else {
        int col = nloc + n * 16 + l16;
        int kh = col >> 6, hd = col & 63;
        if (mode == 1)
          k_ws[(((size_t)bb * N_KV + kh) * S_TOK + ss) * HD + hd] = val;
        else
          v_ws[(((size_t)bb * N_KV + kh) * HD + hd) * S_TOK + ss] = val;
      }
    }
  }
}

// ---------------------------------------------------------------------------
// Kernel 2: attention, split-K wave pairs.
// Block = 4 waves = 2 pairs. Each pair owns 32 q-rows; wave `half` owns key
// tiles [half*16, half*16+16). Pass A partial row-sums combined via LDS;
// pass B writes normalized probs (nontemporal) + partial PV, O combined via LDS.
// grid 1024 (32 heads x 32 row-tiles of 64), block 256.
// ---------------------------------------------------------------------------
__global__ __launch_bounds__(256, 3) void k_attn(
    const f16* __restrict__ q_ws, const f16* __restrict__ k_ws,
    const f16* __restrict__ v_ws, f16* __restrict__ o_ws,
    float* __restrict__ probs) {
  __shared__ f16 plds_all[4][32][72];
  __shared__ float lpart[2][2][32];
  __shared__ float osum[2][32][68];
  const int tid = threadIdx.x;
  const int wave = tid >> 6, lane = tid & 63;
  const int pairi = wave >> 1, half = wave & 1;
  const int l16 = lane & 15, g = lane >> 4;
  const int head = blockIdx.x >> 5;  // b*16+h
  const int rt = blockIdx.x & 31;
  const int b = head >> 4, h = head & 15, kvh = h >> 2;
  const int qrow0 = rt * 64 + pairi * 32;

  const f16* qb = q_ws + ((size_t)head * S_TOK + qrow0) * HD;
  const f16* kb = k_ws + (size_t)(b * N_KV + kvh) * S_TOK * HD;
  const f16* vb = v_ws + (size_t)(b * N_KV + kvh) * HD * S_TOK;  // [hd][s]
  float* pout = probs + (size_t)head * S_TOK * S_TOK + (size_t)qrow0 * S_TOK;
  f16(*plds)[72] = plds_all[wave];

  f16x8 qf[2][2];
#pragma unroll
  for (int mf = 0; mf < 2; ++mf)
#pragma unroll
    for (int ks = 0; ks < 2; ++ks)
      qf[mf][ks] = *(const f16x8*)(qb + (mf * 16 + l16) * HD + ks * 32 + g * 8);

  const int kt0 = half * 16, kt1 = kt0 + 16;

  // ---- pass A: partial row sums of exp over this wave's key half ----
  float lsum[2][4] = {};
  for (int kt = kt0; kt < kt1; ++kt) {
    const f16* kp = kb + (size_t)kt * 64 * HD;
#pragma unroll
    for (int n = 0; n < 4; ++n) {
      f16x8 k0f = *(const f16x8*)(kp + (n * 16 + l16) * HD + g * 8);
      f16x8 k1f = *(const f16x8*)(kp + (n * 16 + l16) * HD + 32 + g * 8);
#pragma unroll
      for (int mf = 0; mf < 2; ++mf) {
        f32x4 s = {};
        s = MFMA_F16(qf[mf][0], k0f, s);
        s = MFMA_F16(qf[mf][1], k1f, s);
#pragma unroll
        for (int r = 0; r < 4; ++r) lsum[mf][r] += exp2f(s[r] * SCL2E);
      }
    }
  }
#pragma unroll
  for (int mf = 0; mf < 2; ++mf)
#pragma unroll
    for (int r = 0; r < 4; ++r) {
      float v = lsum[mf][r];
      v += __shfl_xor(v, 1, 64);
      v += __shfl_xor(v, 2, 64);
      v += __shfl_xor(v, 4, 64);
      v += __shfl_xor(v, 8, 64);
      lsum[mf][r] = v;  // half-range row sum, replicated across 16-lane group
    }
  if (l16 == 0) {
#pragma unroll
    for (int mf = 0; mf < 2; ++mf)
#pragma unroll
      for (int r = 0; r < 4; ++r)
        lpart[pairi][half][mf * 16 + g * 4 + r] = lsum[mf][r];
  }
  __syncthreads();
  float linv[2][4];
#pragma unroll
  for (int mf = 0; mf < 2; ++mf)
#pragma unroll
    for (int r = 0; r < 4; ++r) {
      int row = mf * 16 + g * 4 + r;
      linv[mf][r] = 1.0f / (lpart[pairi][0][row] + lpart[pairi][1][row]);
    }

  // ---- pass B: probs write + partial PV ----
  f32x4 oacc[2][4] = {};
  const int orow = lane >> 4, oq = lane & 15;
  for (int kt = kt0; kt < kt1; ++kt) {
    const f16* kp = kb + (size_t)kt * 64 * HD;
#pragma unroll
    for (int n = 0; n < 4; ++n) {
      f16x8 k0f = *(const f16x8*)(kp + (n * 16 + l16) * HD + g * 8);
      f16x8 k1f = *(const f16x8*)(kp + (n * 16 + l16) * HD + 32 + g * 8);
#pragma unroll
      for (int mf = 0; mf < 2; ++mf) {
        f32x4 s = {};
        s = MFMA_F16(qf[mf][0], k0f, s);
        s = MFMA_F16(qf[mf][1], k1f, s);
#pragma unroll
        for (int r = 0; r < 4; ++r) {
          float p = exp2f(s[r] * SCL2E) * linv[mf][r];
          plds[mf * 16 + g * 4 + r][n * 16 + l16] = (f16)p;
        }
      }
    }
    asm volatile("s_waitcnt lgkmcnt(0)" ::: "memory");  // intra-wave LDS vis
    f16x8 pa[2][2];
#pragma unroll
    for (int mf = 0; mf < 2; ++mf)
#pragma unroll
      for (int ks = 0; ks < 2; ++ks)
        pa[mf][ks] = *(const f16x8*)&plds[mf * 16 + l16][ks * 32 + g * 8];
#pragma unroll
    for (int nh = 0; nh < 4; ++nh) {
      const f16* vp = vb + (size_t)(nh * 16 + l16) * S_TOK + kt * 64;
      f16x8 v0f = *(const f16x8*)(vp + g * 8);
      f16x8 v1f = *(const f16x8*)(vp + 32 + g * 8);
#pragma unroll
      for (int mf = 0; mf < 2; ++mf) {
        oacc[mf][nh] = MFMA_F16(pa[mf][0], v0f, oacc[mf][nh]);
        oacc[mf][nh] = MFMA_F16(pa[mf][1], v1f, oacc[mf][nh]);
      }
    }
    // nontemporal coalesced probs write: each inst covers 4 full 256B rows
#pragma unroll
    for (int it = 0; it < 8; ++it) {
      int rr = it * 4 + orow;
      f16x4 pv = *(const f16x4*)&plds[rr][oq * 4];
      f32x4 ov = {(float)pv[0], (float)pv[1], (float)pv[2], (float)pv[3]};
      __builtin_nontemporal_store(
          ov, (f32x4*)(pout + (size_t)rr * S_TOK + kt * 64 + oq * 4));
    }
    asm volatile("" ::: "memory");  // keep next iter's LDS writes after reads
  }

  // ---- pair O combine ----
  if (half == 1) {
#pragma unroll
    for (int mf = 0; mf < 2; ++mf)
#pragma unroll
      for (int nh = 0; nh < 4; ++nh)
#pragma unroll
        for (int r = 0; r < 4; ++r)
          osum[pairi][mf * 16 + g * 4 + r][nh * 16 + l16] = oacc[mf][nh][r];
  }
  __syncthreads();
  if (half == 0) {
#pragma unroll
    for (int mf = 0; mf < 2; ++mf)
#pragma unroll
      for (int nh = 0; nh < 4; ++nh)
#pragma unroll
        for (int r = 0; r < 4; ++r) {
          int row = mf * 16 + g * 4 + r;
          float v = oacc[mf][nh][r] + osum[pairi][row][nh * 16 + l16];
          o_ws[((size_t)b * S_TOK + qrow0 + row) * 1024 + h * HD + nh * 16 +
               l16] = (f16)v;
        }
  }
}

// ---------------------------------------------------------------------------
// Kernel 3: O projection (f16 weights). o_ws @ o_w + o_b -> d_out fp32
// ---------------------------------------------------------------------------
__global__ __launch_bounds__(256) void k_oproj(
    const f16* __restrict__ a, const f16* __restrict__ o_w,
    const float* __restrict__ o_b, float* __restrict__ out) {
  __shared__ f16 wb[64][72];
  const int tid = threadIdx.x;
  const int wave = tid >> 6, lane = tid & 63;
  const int l16 = lane & 15, g = lane >> 4;
  const int m0 = blockIdx.x * 64, n0 = blockIdx.y * 64;
  f32x4 acc[4] = {};
  const int kk = (tid >> 4) * 4, nn = (tid & 15) * 4;
  for (int k0 = 0; k0 < 1024; k0 += 64) {
    const f16* wp = o_w + (size_t)(k0 + kk) * 1024 + n0 + nn;
    f16x4 w0 = *(const f16x4*)(wp);
    f16x4 w1 = *(const f16x4*)(wp + 1024);
    f16x4 w2 = *(const f16x4*)(wp + 2048);
    f16x4 w3 = *(const f16x4*)(wp + 3072);
    __syncthreads();
    *(f16x4*)&wb[nn + 0][kk] = f16x4{w0[0], w1[0], w2[0], w3[0]};
    *(f16x4*)&wb[nn + 1][kk] = f16x4{w0[1], w1[1], w2[1], w3[1]};
    *(f16x4*)&wb[nn + 2][kk] = f16x4{w0[2], w1[2], w2[2], w3[2]};
    *(f16x4*)&wb[nn + 3][kk] = f16x4{w0[3], w1[3], w2[3], w3[3]};
    __syncthreads();
    const f16* ap = a + (size_t)(m0 + wave * 16 + l16) * 1024 + k0 + g * 8;
#pragma unroll
    for (int ks = 0; ks < 2; ++ks) {
      f16x8 af = *(const f16x8*)(ap + ks * 32);
#pragma unroll
      for (int n = 0; n < 4; ++n) {
        f16x8 bf = *(const f16x8*)&wb[n * 16 + l16][ks * 32 + g * 8];
        acc[n] = MFMA_F16(af, bf, acc[n]);
      }
    }
  }
#pragma unroll
  for (int n = 0; n < 4; ++n) {
    float bsc = o_b[n0 + n * 16 + l16];
#pragma unroll
    for (int r = 0; r < 4; ++r) {
      int row = m0 + wave * 16 + g * 4 + r;
      out[(size_t)row * 1024 + n0 + n * 16 + l16] = acc[n][r] + bsc;
    }
  }
}

extern "C" void kernel_launch(void* const* d_in, const int* in_sizes, int n_in,
                              void* d_out, int out_size, void* d_ws,
                              size_t ws_size, hipStream_t stream) {
  (void)in_sizes; (void)n_in; (void)out_size; (void)ws_size;
  const float* x    = (const float*)d_in[0];
  const float* cosp = (const float*)d_in[1];
  const float* sinp = (const float*)d_in[2];
  const float* q_w  = (const float*)d_in[3];
  const float* q_b  = (const float*)d_in[4];
  const float* k_w  = (const float*)d_in[5];
  const float* v_w  = (const float*)d_in[6];
  const float* v_b  = (const float*)d_in[7];
  const float* o_w  = (const float*)d_in[8];
  const float* o_b  = (const float*)d_in[9];

  f16* ws = (f16*)d_ws;
  f16* x16  = ws + OFF_X16;
  f16* qw16 = ws + OFF_QW;
  f16* kw16 = ws + OFF_KW;
  f16* vw16 = ws + OFF_VW;
  f16* ow16 = ws + OFF_OW;
  f16* q_ws = ws + OFF_QS;
  f16* k_ws = ws + OFF_KS;
  f16* v_ws = ws + OFF_VS;
  f16* o_ws = ws + OFF_OS;
  float* out = (float*)d_out;          // attn_output [0, 4194304)
  float* probs = out + 4194304;        // attn_weights

  k_cvt<<<dim3((CVT_TOTAL / 4 + 255) / 256), 256, 0, stream>>>(
      x, q_w, k_w, v_w, o_w, ws);
  k_qkv<<<dim3(64, 24), 256, 0, stream>>>(x16, cosp, sinp, qw16, q_b, kw16,
                                          vw16, v_b, q_ws, k_ws, v_ws);
  k_attn<<<dim3(1024), 256, 0, stream>>>(q_ws, k_ws, v_ws, o_ws, probs);
  k_oproj<<<dim3(64, 16), 256, 0, stream>>>(o_ws, ow16, o_b, out);
}